// Round 8
// baseline (891.381 us; speedup 1.0000x reference)
//
#include <hip/hip_runtime.h>
#include <hip/hip_cooperative_groups.h>

namespace cg = cooperative_groups;

#define N_NODES 50000
#define N_EDGES 600000
#define DIM 128
#define EPS 1e-5f

#define NPB 32              // nodes per gemm tile (16 KB LDS)
#define NTHR 256
#define MAXBLK 1024
#define SEG 1024            // counts per scan segment
#define NSEG ((N_NODES + SEG - 1) / SEG)   // 49

// s[n][d] = t*W[0][d] + b[d] + sum_k xin[n][k] * W[k+1][d]
__device__ __forceinline__ void gemm_stage(
    const float* __restrict__ xin, const float* __restrict__ W,
    const float* __restrict__ bias, float tval,
    float* __restrict__ outp, float xs[NPB][DIM], int nblk)
{
    const int tid = threadIdx.x;
    const int ntiles = (N_NODES + NPB - 1) / NPB;   // 1563
    const float4* xin4 = (const float4*)xin;
    for (int tile = blockIdx.x; tile < ntiles; tile += nblk) {
        const int nb = tile * NPB;
#pragma unroll
        for (int i = 0; i < 4; ++i) {
            int f4 = tid + i * NTHR;           // 0..1023
            int nl = f4 >> 5;
            int q  = f4 & 31;
            int node = nb + nl;
            float4 v = make_float4(0.f, 0.f, 0.f, 0.f);
            if (node < N_NODES) v = xin4[(size_t)node * 32 + q];
            *(float4*)&xs[nl][q * 4] = v;
        }
        __syncthreads();

        const int dq   = (tid & 31) * 4;
        const int nloc = (tid >> 5) * 4;

        float4 acc[4];
#pragma unroll
        for (int i = 0; i < 4; ++i) acc[i] = make_float4(0.f, 0.f, 0.f, 0.f);

        for (int k = 0; k < DIM; k += 4) {
            float4 w0 = *(const float4*)&W[(k + 1) * DIM + dq];
            float4 w1 = *(const float4*)&W[(k + 2) * DIM + dq];
            float4 w2 = *(const float4*)&W[(k + 3) * DIM + dq];
            float4 w3 = *(const float4*)&W[(k + 4) * DIM + dq];
#pragma unroll
            for (int i = 0; i < 4; ++i) {
                float4 xv = *(const float4*)&xs[nloc + i][k];
                acc[i].x = fmaf(xv.x, w0.x, fmaf(xv.y, w1.x, fmaf(xv.z, w2.x, fmaf(xv.w, w3.x, acc[i].x))));
                acc[i].y = fmaf(xv.x, w0.y, fmaf(xv.y, w1.y, fmaf(xv.z, w2.y, fmaf(xv.w, w3.y, acc[i].y))));
                acc[i].z = fmaf(xv.x, w0.z, fmaf(xv.y, w1.z, fmaf(xv.z, w2.z, fmaf(xv.w, w3.z, acc[i].z))));
                acc[i].w = fmaf(xv.x, w0.w, fmaf(xv.y, w1.w, fmaf(xv.z, w2.w, fmaf(xv.w, w3.w, acc[i].w))));
            }
        }

        float4 w0r = *(const float4*)&W[dq];        // t-row (row 0 of W)
        float4 bb  = *(const float4*)&bias[dq];
#pragma unroll
        for (int i = 0; i < 4; ++i) {
            int node = nb + nloc + i;
            if (node < N_NODES) {
                float4 r;
                r.x = acc[i].x + tval * w0r.x + bb.x;
                r.y = acc[i].y + tval * w0r.y + bb.y;
                r.z = acc[i].z + tval * w0r.z + bb.z;
                r.w = acc[i].w + tval * w0r.w + bb.w;
                *(float4*)&outp[(size_t)node * DIM + dq] = r;
            }
        }
        __syncthreads();   // protect xs before next tile's staging
    }
}

// One 64-lane wave per node: half = edge parity, quad = float4 index.
__device__ __forceinline__ void gather_stage(
    const float4* __restrict__ s4, const int* __restrict__ rowptr,
    const int* __restrict__ eid, const float* __restrict__ gamma,
    const float* __restrict__ beta, float* __restrict__ outp, int nblk)
{
    const int wave0  = blockIdx.x * (NTHR / 64) + (threadIdx.x >> 6);
    const int nwaves = nblk * (NTHR / 64);
    const int lane = threadIdx.x & 63;
    const int half = lane >> 5;
    const int quad = lane & 31;
    const float4 gm = *(const float4*)&gamma[quad * 4];
    const float4 bt = *(const float4*)&beta[quad * 4];

    for (int node = wave0; node < N_NODES; node += nwaves) {
        int beg = rowptr[node];
        int end = rowptr[node + 1];

        float4 acc = make_float4(0.f, 0.f, 0.f, 0.f);
        int j = beg + half;
        for (; j + 2 < end; j += 4) {           // 4 edges/wave-iter (2 per half)
            int i0 = eid[j];
            int i1 = eid[j + 2];
            float4 v0 = s4[(size_t)i0 * 32 + quad];
            float4 v1 = s4[(size_t)i1 * 32 + quad];
            acc.x += v0.x + v1.x;
            acc.y += v0.y + v1.y;
            acc.z += v0.z + v1.z;
            acc.w += v0.w + v1.w;
        }
        for (; j < end; j += 2) {
            float4 v0 = s4[(size_t)eid[j] * 32 + quad];
            acc.x += v0.x;
            acc.y += v0.y;
            acc.z += v0.z;
            acc.w += v0.w;
        }

        acc.x += __shfl_xor(acc.x, 32);
        acc.y += __shfl_xor(acc.y, 32);
        acc.z += __shfl_xor(acc.z, 32);
        acc.w += __shfl_xor(acc.w, 32);

        if (half == 0) {
            int deg = end - beg;
            float inv = (deg > 0) ? (1.0f / (float)deg) : 0.0f;
            float ax = fmaxf(acc.x * inv, 0.f);
            float ay = fmaxf(acc.y * inv, 0.f);
            float az = fmaxf(acc.z * inv, 0.f);
            float aw = fmaxf(acc.w * inv, 0.f);
            float mu = 0.25f * (ax + ay + az + aw);
            float dx = ax - mu, dy = ay - mu, dz = az - mu, dw = aw - mu;
            float var = 0.25f * (dx * dx + dy * dy + dz * dz + dw * dw);
            float rs = rsqrtf(var + EPS);
            float4 r;
            r.x = dx * rs * gm.x + bt.x;
            r.y = dy * rs * gm.y + bt.y;
            r.z = dz * rs * gm.z + bt.z;
            r.w = dw * rs * gm.w + bt.w;
            *(float4*)&outp[(size_t)node * DIM + quad * 4] = r;
        }
    }
}

__global__ __launch_bounds__(NTHR, 4) void fused_kernel(
    const float* __restrict__ t, const float* __restrict__ x,
    const int* __restrict__ src, const int* __restrict__ tgt,
    const float* __restrict__ W1, const float* __restrict__ b1,
    const float* __restrict__ W2, const float* __restrict__ b2,
    const float* __restrict__ gamma1, const float* __restrict__ beta1,
    const float* __restrict__ gamma2, const float* __restrict__ beta2,
    float* __restrict__ out, float* __restrict__ s_buf,
    int* __restrict__ rowptr, int* __restrict__ cursor,
    int* __restrict__ bsum, int* __restrict__ eid, int nblk)
{
    cg::grid_group grid = cg::this_grid();
    __shared__ float xs[NPB][DIM];    // 16 KB (gemm staging)
    __shared__ int   ish[NTHR];       // 1 KB  (scan)
    const int tid  = threadIdx.x;
    const int gtid = blockIdx.x * NTHR + tid;
    const int gsz  = nblk * NTHR;

    // ---- stage 0: zero counts ----
    for (int i = gtid; i < N_NODES; i += gsz) cursor[i] = 0;
    grid.sync();

    // ---- stage 1: histogram of tgt ----
    for (int e = gtid; e < N_EDGES; e += gsz) atomicAdd(&cursor[tgt[e]], 1);
    grid.sync();

    // ---- stage 2a: per-segment sums (segment = 1024 counts) ----
    const int n4 = N_NODES / 4;                     // 12500
    for (int seg = blockIdx.x; seg < NSEG; seg += nblk) {
        int idx4 = seg * 256 + tid;
        int4 c = make_int4(0, 0, 0, 0);
        if (idx4 < n4) c = ((const int4*)cursor)[idx4];
        ish[tid] = c.x + c.y + c.z + c.w;
        __syncthreads();
#pragma unroll
        for (int off2 = 128; off2 > 0; off2 >>= 1) {
            if (tid < off2) ish[tid] += ish[tid + off2];
            __syncthreads();
        }
        if (tid == 0) bsum[seg] = ish[0];
        __syncthreads();
    }
    grid.sync();

    // ---- stage 2b: block 0, one wave scans bsum[NSEG] (NSEG=49 <= 64) ----
    if (blockIdx.x == 0 && tid < 64) {
        int v = (tid < NSEG) ? bsum[tid] : 0;
        int incl = v;
#pragma unroll
        for (int off2 = 1; off2 < 64; off2 <<= 1) {
            int u = __shfl_up(incl, off2);
            if ((threadIdx.x & 63) >= off2) incl += u;
        }
        if (tid < NSEG) bsum[tid] = incl - v;       // exclusive
    }
    grid.sync();

    // ---- stage 2c: write rowptr per segment ----
    for (int seg = blockIdx.x; seg < NSEG; seg += nblk) {
        int idx4 = seg * 256 + tid;
        int4 c = make_int4(0, 0, 0, 0);
        if (idx4 < n4) c = ((const int4*)cursor)[idx4];
        int tsum = c.x + c.y + c.z + c.w;
        ish[tid] = tsum;
        __syncthreads();
#pragma unroll
        for (int off2 = 1; off2 < NTHR; off2 <<= 1) {
            int v = (tid >= off2) ? ish[tid - off2] : 0;
            __syncthreads();
            ish[tid] += v;
            __syncthreads();
        }
        int base = bsum[seg] + ish[tid] - tsum;
        if (idx4 < n4) {
            int4 r;
            r.x = base;
            r.y = base + c.x;
            r.z = r.y + c.y;
            r.w = r.z + c.z;
            ((int4*)rowptr)[idx4] = r;
            if (idx4 == n4 - 1) rowptr[N_NODES] = r.w + c.w;
        }
        __syncthreads();
    }
    grid.sync();

    // ---- stage 3: place edges (cursor: counts -> 0) ----
    for (int e = gtid; e < N_EDGES; e += gsz) {
        int tg = tgt[e];
        int idx = atomicSub(&cursor[tg], 1) - 1;
        eid[rowptr[tg] + idx] = src[e];
    }
    grid.sync();

    const float tval = *t;

    // ---- layer 1 ----
    gemm_stage(x, W1, b1, tval, s_buf, xs, nblk);
    grid.sync();
    gather_stage((const float4*)s_buf, rowptr, eid, gamma1, beta1, out, nblk);
    grid.sync();

    // ---- layer 2 ----
    gemm_stage(out, W2, b2, tval, s_buf, xs, nblk);
    grid.sync();
    gather_stage((const float4*)s_buf, rowptr, eid, gamma2, beta2, out, nblk);
}

extern "C" void kernel_launch(void* const* d_in, const int* in_sizes, int n_in,
                              void* d_out, int out_size, void* d_ws, size_t ws_size,
                              hipStream_t stream) {
    const float* t      = (const float*)d_in[0];
    const float* x      = (const float*)d_in[1];
    const int*   src    = (const int*)d_in[2];
    const int*   tgt    = (const int*)d_in[3];
    const float* W1     = (const float*)d_in[5];
    const float* b1     = (const float*)d_in[6];
    const float* W2     = (const float*)d_in[7];
    const float* b2     = (const float*)d_in[8];
    const float* gamma1 = (const float*)d_in[9];
    const float* beta1  = (const float*)d_in[10];
    const float* gamma2 = (const float*)d_in[11];
    const float* beta2  = (const float*)d_in[12];
    float* out = (float*)d_out;

    const size_t NODE_BYTES = (size_t)N_NODES * DIM * sizeof(float);  // 25.6 MB
    char* ws = (char*)d_ws;
    size_t off = 0;
    float* s_buf  = (float*)(ws + off); off += NODE_BYTES;
    int*   rowptr = (int*)(ws + off);   off += ((size_t)N_NODES + 4) * 4;
    off = (off + 255) & ~(size_t)255;
    int*   cursor = (int*)(ws + off);   off += (size_t)N_NODES * 4;
    off = (off + 255) & ~(size_t)255;
    int*   bsum   = (int*)(ws + off);   off += 256 * 4;
    off = (off + 255) & ~(size_t)255;
    int*   eid    = (int*)(ws + off);   off += (size_t)N_EDGES * 4;

    // size the cooperative grid to guaranteed co-residency
    int dev = 0;
    hipGetDevice(&dev);
    int num_cu = 256;
    hipDeviceGetAttribute(&num_cu, hipDeviceAttributeMultiprocessorCount, dev);
    int blocks_per_cu = 1;
    hipOccupancyMaxActiveBlocksPerMultiprocessor(&blocks_per_cu, fused_kernel, NTHR, 0);
    int nblk = num_cu * (blocks_per_cu > 0 ? blocks_per_cu : 1);
    if (nblk > MAXBLK) nblk = MAXBLK;
    if (nblk < 64) nblk = 64;

    void* args[] = {
        (void*)&t, (void*)&x, (void*)&src, (void*)&tgt,
        (void*)&W1, (void*)&b1, (void*)&W2, (void*)&b2,
        (void*)&gamma1, (void*)&beta1, (void*)&gamma2, (void*)&beta2,
        (void*)&out, (void*)&s_buf, (void*)&rowptr, (void*)&cursor,
        (void*)&bsum, (void*)&eid, (void*)&nblk
    };
    hipLaunchCooperativeKernel(fused_kernel, dim3(nblk), dim3(NTHR), args, 0, stream);
}

// Round 9
// 422.531 us; speedup vs baseline: 2.1096x; 2.1096x over previous
//
#include <hip/hip_runtime.h>
#include <hip/hip_bf16.h>

#define N_NODES 50000
#define N_EDGES 600000
#define DIM 128
#define EPS 1e-5f

#define NPB 64              // nodes per block in GEMM
#define SCAN_CHUNK 1024
#define SCAN_NB ((N_NODES + SCAN_CHUNK - 1) / SCAN_CHUNK)   // 49
#define NSLICE 8            // channel slices (16 ch each) — one per XCD
#define GPB 320             // blocks per slice in gather (grid = 2560)

// s_sliced[slice][n][16ch]: slice-major so each slice is 3.2 MB (L2-resident per XCD)
// float4 offset for (node, quad q=0..31): (q>>2)*(N_NODES*4) + node*4 + (q&3)
__global__ __launch_bounds__(256) void gemm_kernel(
    const float* __restrict__ xin, const float* __restrict__ W,
    const float* __restrict__ bias, const float* __restrict__ tptr,
    float4* __restrict__ s_sliced, int N)
{
    __shared__ float xs[NPB][DIM];     // 32 KB
    const int tid = threadIdx.x;
    const int nb = blockIdx.x * NPB;

    const float4* xin4 = (const float4*)xin;
#pragma unroll
    for (int i = 0; i < 8; ++i) {
        int f4 = tid + i * 256;            // 0..2047
        int nl = f4 >> 5;
        int q  = f4 & 31;
        int node = nb + nl;
        float4 v = make_float4(0.f, 0.f, 0.f, 0.f);
        if (node < N) v = xin4[(size_t)node * 32 + q];
        *(float4*)&xs[nl][q * 4] = v;
    }
    __syncthreads();

    const int quad = tid & 31;             // float4 index 0..31
    const int dq   = quad * 4;
    const int nloc = (tid >> 5) * 8;
    const int slice = quad >> 2;           // 0..7
    const int qin   = quad & 3;            // quad within slice

    float4 acc[8];
#pragma unroll
    for (int i = 0; i < 8; ++i) acc[i] = make_float4(0.f, 0.f, 0.f, 0.f);

    for (int k = 0; k < DIM; k += 4) {
        float4 w0 = *(const float4*)&W[(k + 1) * DIM + dq];
        float4 w1 = *(const float4*)&W[(k + 2) * DIM + dq];
        float4 w2 = *(const float4*)&W[(k + 3) * DIM + dq];
        float4 w3 = *(const float4*)&W[(k + 4) * DIM + dq];
#pragma unroll
        for (int i = 0; i < 8; ++i) {
            float4 xv = *(const float4*)&xs[nloc + i][k];
            acc[i].x = fmaf(xv.x, w0.x, fmaf(xv.y, w1.x, fmaf(xv.z, w2.x, fmaf(xv.w, w3.x, acc[i].x))));
            acc[i].y = fmaf(xv.x, w0.y, fmaf(xv.y, w1.y, fmaf(xv.z, w2.y, fmaf(xv.w, w3.y, acc[i].y))));
            acc[i].z = fmaf(xv.x, w0.z, fmaf(xv.y, w1.z, fmaf(xv.z, w2.z, fmaf(xv.w, w3.z, acc[i].z))));
            acc[i].w = fmaf(xv.x, w0.w, fmaf(xv.y, w1.w, fmaf(xv.z, w2.w, fmaf(xv.w, w3.w, acc[i].w))));
        }
    }

    const float tval = *tptr;
    float4 w0r = *(const float4*)&W[dq];        // t-row (row 0 of W)
    float4 bb  = *(const float4*)&bias[dq];
    const size_t sbase = (size_t)slice * N_NODES * 4 + qin;
#pragma unroll
    for (int i = 0; i < 8; ++i) {
        int node = nb + nloc + i;
        if (node < N) {
            float4 r;
            r.x = acc[i].x + tval * w0r.x + bb.x;
            r.y = acc[i].y + tval * w0r.y + bb.y;
            r.z = acc[i].z + tval * w0r.z + bb.z;
            r.w = acc[i].w + tval * w0r.w + bb.w;
            s_sliced[sbase + (size_t)node * 4] = r;
        }
    }
}

// ---- CSR build ----
__global__ __launch_bounds__(256) void hist_kernel(
    const int* __restrict__ tgt, int* __restrict__ counts, int E)
{
    int e = blockIdx.x * 256 + threadIdx.x;
    if (e < E) atomicAdd(&counts[tgt[e]], 1);
}

__global__ __launch_bounds__(256) void scan_pass1(
    const int* __restrict__ counts, int* __restrict__ bsum, int N)
{
    __shared__ int sh[256];
    const int tid = threadIdx.x;
    const int n4 = N / 4;
    int idx4 = blockIdx.x * 256 + tid;
    int4 c = make_int4(0, 0, 0, 0);
    if (idx4 < n4) c = ((const int4*)counts)[idx4];
    sh[tid] = c.x + c.y + c.z + c.w;
    __syncthreads();
#pragma unroll
    for (int off = 128; off > 0; off >>= 1) {
        if (tid < off) sh[tid] += sh[tid + off];
        __syncthreads();
    }
    if (tid == 0) bsum[blockIdx.x] = sh[0];
}

__global__ __launch_bounds__(64) void scan_bsum(int* __restrict__ bsum, int nb)
{
    int lane = threadIdx.x;
    int v = (lane < nb) ? bsum[lane] : 0;
    int incl = v;
#pragma unroll
    for (int off = 1; off < 64; off <<= 1) {
        int u = __shfl_up(incl, off);
        if (lane >= off) incl += u;
    }
    if (lane < nb) bsum[lane] = incl - v;      // exclusive
}

__global__ __launch_bounds__(256) void scan_pass3(
    const int* __restrict__ counts, const int* __restrict__ bsum,
    int* __restrict__ rowptr, int N)
{
    __shared__ int sh[256];
    const int tid = threadIdx.x;
    const int n4 = N / 4;
    int idx4 = blockIdx.x * 256 + tid;
    int4 c = make_int4(0, 0, 0, 0);
    if (idx4 < n4) c = ((const int4*)counts)[idx4];
    int tsum = c.x + c.y + c.z + c.w;
    sh[tid] = tsum;
    __syncthreads();
#pragma unroll
    for (int off = 1; off < 256; off <<= 1) {
        int v = (tid >= off) ? sh[tid - off] : 0;
        __syncthreads();
        sh[tid] += v;
        __syncthreads();
    }
    int base = bsum[blockIdx.x] + sh[tid] - tsum;
    if (idx4 < n4) {
        int4 r;
        r.x = base;
        r.y = base + c.x;
        r.z = r.y + c.y;
        r.w = r.z + c.z;
        ((int4*)rowptr)[idx4] = r;
        if (idx4 == n4 - 1) rowptr[N] = r.w + c.w;
    }
}

__global__ __launch_bounds__(256) void place_kernel(
    const int* __restrict__ src, const int* __restrict__ tgt,
    const int* __restrict__ rowptr,
    int* __restrict__ cursor, int* __restrict__ eid, int E)
{
    int e = blockIdx.x * 256 + threadIdx.x;
    if (e >= E) return;
    int t = tgt[e];
    int idx = atomicSub(&cursor[t], 1) - 1;
    eid[rowptr[t] + idx] = src[e];
}

// XCD-sliced gather: slice = blockIdx % 8 (round-robin block->XCD mapping keeps
// each 3.2 MB slice table L2-resident on one XCD). One wave per node:
// lane = e_idx*4 + qin; 16 edges in flight; butterfly-reduce over e_idx.
__global__ __launch_bounds__(256) void gather_gn_kernel(
    const float4* __restrict__ s_sliced, const int* __restrict__ rowptr,
    const int* __restrict__ eid,
    const float* __restrict__ gamma, const float* __restrict__ beta,
    float* __restrict__ out, int N)
{
    const int slice = blockIdx.x & 7;          // = blockIdx.x % NSLICE
    const int sblk  = blockIdx.x >> 3;         // block within slice: 0..GPB-1
    const int lane  = threadIdx.x & 63;
    const int wave  = threadIdx.x >> 6;        // 0..3
    const int e_idx = lane >> 2;               // 0..15
    const int qin   = lane & 3;                // quad within slice

    const float4* stab = s_sliced + (size_t)slice * N_NODES * 4;
    const int gch = slice * 16 + qin * 4;      // first channel of my GN group
    const float4 gm = *(const float4*)&gamma[gch];
    const float4 bt = *(const float4*)&beta[gch];

    const int wave0  = sblk * 4 + wave;
    const int nwaves = GPB * 4;

    for (int node = wave0; node < N; node += nwaves) {
        int beg = rowptr[node];
        int end = rowptr[node + 1];

        float4 acc = make_float4(0.f, 0.f, 0.f, 0.f);
        for (int e = beg + e_idx; e < end; e += 16) {
            int s = eid[e];
            float4 v = stab[(size_t)s * 4 + qin];
            acc.x += v.x;
            acc.y += v.y;
            acc.z += v.z;
            acc.w += v.w;
        }

        // reduce over e_idx (lane bits 2..5)
#pragma unroll
        for (int m = 4; m < 64; m <<= 1) {
            acc.x += __shfl_xor(acc.x, m);
            acc.y += __shfl_xor(acc.y, m);
            acc.z += __shfl_xor(acc.z, m);
            acc.w += __shfl_xor(acc.w, m);
        }

        if (e_idx == 0) {
            int deg = end - beg;
            float inv = (deg > 0) ? (1.0f / (float)deg) : 0.0f;
            float ax = fmaxf(acc.x * inv, 0.f);
            float ay = fmaxf(acc.y * inv, 0.f);
            float az = fmaxf(acc.z * inv, 0.f);
            float aw = fmaxf(acc.w * inv, 0.f);
            float mu = 0.25f * (ax + ay + az + aw);
            float dx = ax - mu, dy = ay - mu, dz = az - mu, dw = aw - mu;
            float var = 0.25f * (dx * dx + dy * dy + dz * dz + dw * dw);
            float rs = rsqrtf(var + EPS);
            float4 r;
            r.x = dx * rs * gm.x + bt.x;
            r.y = dy * rs * gm.y + bt.y;
            r.z = dz * rs * gm.z + bt.z;
            r.w = dw * rs * gm.w + bt.w;
            *(float4*)&out[(size_t)node * DIM + gch] = r;
        }
    }
}

extern "C" void kernel_launch(void* const* d_in, const int* in_sizes, int n_in,
                              void* d_out, int out_size, void* d_ws, size_t ws_size,
                              hipStream_t stream) {
    const float* t      = (const float*)d_in[0];
    const float* x      = (const float*)d_in[1];
    const int*   src    = (const int*)d_in[2];
    const int*   tgt    = (const int*)d_in[3];
    const float* W1     = (const float*)d_in[5];
    const float* b1     = (const float*)d_in[6];
    const float* W2     = (const float*)d_in[7];
    const float* b2     = (const float*)d_in[8];
    const float* gamma1 = (const float*)d_in[9];
    const float* beta1  = (const float*)d_in[10];
    const float* gamma2 = (const float*)d_in[11];
    const float* beta2  = (const float*)d_in[12];
    float* out = (float*)d_out;

    const size_t NODE_BYTES = (size_t)N_NODES * DIM * sizeof(float);  // 25.6 MB
    char* ws = (char*)d_ws;
    size_t off = 0;
    float4* s_sliced = (float4*)(ws + off); off += NODE_BYTES;            // 25.6 MB
    int*    rowptr   = (int*)(ws + off);    off += ((size_t)N_NODES + 4) * 4;
    off = (off + 255) & ~(size_t)255;
    int*    cursor   = (int*)(ws + off);    off += (size_t)N_NODES * 4;
    off = (off + 255) & ~(size_t)255;
    int*    bsum     = (int*)(ws + off);    off += 64 * 4;
    off = (off + 255) & ~(size_t)255;
    int*    eid      = (int*)(ws + off);    off += (size_t)N_EDGES * 4;   // 2.4 MB

    const int gemm_grid   = (N_NODES + NPB - 1) / NPB;     // 782
    const int edge_grid   = (N_EDGES + 255) / 256;         // 2344
    const int gather_grid = NSLICE * GPB;                  // 2560

    // ---- CSR build (shared by both layers) ----
    hipMemsetAsync(cursor, 0, (size_t)N_NODES * 4, stream);
    hist_kernel<<<edge_grid, 256, 0, stream>>>(tgt, cursor, N_EDGES);      // cursor = counts
    scan_pass1<<<SCAN_NB, 256, 0, stream>>>(cursor, bsum, N_NODES);
    scan_bsum<<<1, 64, 0, stream>>>(bsum, SCAN_NB);
    scan_pass3<<<SCAN_NB, 256, 0, stream>>>(cursor, bsum, rowptr, N_NODES);
    place_kernel<<<edge_grid, 256, 0, stream>>>(src, tgt, rowptr, cursor, eid, N_EDGES);

    // ---- layer 1 ----  (h lives in d_out; gemm2 consumes it before gather2 overwrites)
    gemm_kernel<<<gemm_grid, 256, 0, stream>>>(x, W1, b1, t, s_sliced, N_NODES);
    gather_gn_kernel<<<gather_grid, 256, 0, stream>>>(s_sliced, rowptr, eid, gamma1, beta1, out, N_NODES);

    // ---- layer 2 ----
    gemm_kernel<<<gemm_grid, 256, 0, stream>>>(out, W2, b2, t, s_sliced, N_NODES);
    gather_gn_kernel<<<gather_grid, 256, 0, stream>>>(s_sliced, rowptr, eid, gamma2, beta2, out, N_NODES);
}

// Round 10
// 307.727 us; speedup vs baseline: 2.8967x; 1.3731x over previous
//
#include <hip/hip_runtime.h>
#include <hip/hip_bf16.h>

#define N_NODES 50000
#define N_EDGES 600000
#define DIM 128
#define EPS 1e-5f

#define NPB 64              // nodes per block in GEMM
#define SCAN_CHUNK 1024
#define SCAN_NB ((N_NODES + SCAN_CHUNK - 1) / SCAN_CHUNK)   // 49
#define NSLICE 8            // channel slices (16 ch each) — one per XCD
#define GPB 256             // blocks per slice in gather (grid = 2048)

// s_sliced[slice][n][16ch]: slice-major so each slice is 3.2 MB (L2-resident per XCD)
__global__ __launch_bounds__(256) void gemm_kernel(
    const float* __restrict__ xin, const float* __restrict__ W,
    const float* __restrict__ bias, const float* __restrict__ tptr,
    float4* __restrict__ s_sliced, int N)
{
    __shared__ float xs[NPB][DIM];     // 32 KB
    const int tid = threadIdx.x;
    const int nb = blockIdx.x * NPB;

    const float4* xin4 = (const float4*)xin;
#pragma unroll
    for (int i = 0; i < 8; ++i) {
        int f4 = tid + i * 256;            // 0..2047
        int nl = f4 >> 5;
        int q  = f4 & 31;
        int node = nb + nl;
        float4 v = make_float4(0.f, 0.f, 0.f, 0.f);
        if (node < N) v = xin4[(size_t)node * 32 + q];
        *(float4*)&xs[nl][q * 4] = v;
    }
    __syncthreads();

    const int quad = tid & 31;             // float4 index 0..31
    const int dq   = quad * 4;
    const int nloc = (tid >> 5) * 8;
    const int slice = quad >> 2;           // 0..7
    const int qin   = quad & 3;            // quad within slice

    float4 acc[8];
#pragma unroll
    for (int i = 0; i < 8; ++i) acc[i] = make_float4(0.f, 0.f, 0.f, 0.f);

    for (int k = 0; k < DIM; k += 4) {
        float4 w0 = *(const float4*)&W[(k + 1) * DIM + dq];
        float4 w1 = *(const float4*)&W[(k + 2) * DIM + dq];
        float4 w2 = *(const float4*)&W[(k + 3) * DIM + dq];
        float4 w3 = *(const float4*)&W[(k + 4) * DIM + dq];
#pragma unroll
        for (int i = 0; i < 8; ++i) {
            float4 xv = *(const float4*)&xs[nloc + i][k];
            acc[i].x = fmaf(xv.x, w0.x, fmaf(xv.y, w1.x, fmaf(xv.z, w2.x, fmaf(xv.w, w3.x, acc[i].x))));
            acc[i].y = fmaf(xv.x, w0.y, fmaf(xv.y, w1.y, fmaf(xv.z, w2.y, fmaf(xv.w, w3.y, acc[i].y))));
            acc[i].z = fmaf(xv.x, w0.z, fmaf(xv.y, w1.z, fmaf(xv.z, w2.z, fmaf(xv.w, w3.z, acc[i].z))));
            acc[i].w = fmaf(xv.x, w0.w, fmaf(xv.y, w1.w, fmaf(xv.z, w2.w, fmaf(xv.w, w3.w, acc[i].w))));
        }
    }

    const float tval = *tptr;
    float4 w0r = *(const float4*)&W[dq];        // t-row (row 0 of W)
    float4 bb  = *(const float4*)&bias[dq];
    const size_t sbase = (size_t)slice * N_NODES * 4 + qin;
#pragma unroll
    for (int i = 0; i < 8; ++i) {
        int node = nb + nloc + i;
        if (node < N) {
            float4 r;
            r.x = acc[i].x + tval * w0r.x + bb.x;
            r.y = acc[i].y + tval * w0r.y + bb.y;
            r.z = acc[i].z + tval * w0r.z + bb.z;
            r.w = acc[i].w + tval * w0r.w + bb.w;
            s_sliced[sbase + (size_t)node * 4] = r;
        }
    }
}

// ---- CSR build ----
__global__ __launch_bounds__(256) void hist_kernel(
    const int* __restrict__ tgt, int* __restrict__ counts, int E)
{
    int e = blockIdx.x * 256 + threadIdx.x;
    if (e < E) atomicAdd(&counts[tgt[e]], 1);
}

// pass 1 + merged bsum-scan: per-block sums; LAST finishing block (ticket)
// exclusive-scans bsum[49] in one wave.
__global__ __launch_bounds__(256) void scan_pass1(
    const int* __restrict__ counts, int* __restrict__ bsum,
    int* __restrict__ done, int N)
{
    __shared__ int sh[256];
    __shared__ int ticket;
    const int tid = threadIdx.x;
    const int n4 = N / 4;
    int idx4 = blockIdx.x * 256 + tid;
    int4 c = make_int4(0, 0, 0, 0);
    if (idx4 < n4) c = ((const int4*)counts)[idx4];
    sh[tid] = c.x + c.y + c.z + c.w;
    __syncthreads();
#pragma unroll
    for (int off = 128; off > 0; off >>= 1) {
        if (tid < off) sh[tid] += sh[tid + off];
        __syncthreads();
    }
    if (tid == 0) {
        bsum[blockIdx.x] = sh[0];
        __threadfence();                      // publish bsum before ticket
        ticket = atomicAdd(done, 1);
    }
    __syncthreads();
    if (ticket == SCAN_NB - 1 && tid < 64) {  // last block: scan bsum
        __threadfence();                      // acquire others' bsum writes
        int v = (tid < SCAN_NB) ? bsum[tid] : 0;
        int incl = v;
#pragma unroll
        for (int off = 1; off < 64; off <<= 1) {
            int u = __shfl_up(incl, off);
            if ((threadIdx.x & 63) >= off) incl += u;
        }
        if (tid < SCAN_NB) bsum[tid] = incl - v;   // exclusive
    }
}

__global__ __launch_bounds__(256) void scan_pass3(
    const int* __restrict__ counts, const int* __restrict__ bsum,
    int* __restrict__ rowptr, int N)
{
    __shared__ int sh[256];
    const int tid = threadIdx.x;
    const int n4 = N / 4;
    int idx4 = blockIdx.x * 256 + tid;
    int4 c = make_int4(0, 0, 0, 0);
    if (idx4 < n4) c = ((const int4*)counts)[idx4];
    int tsum = c.x + c.y + c.z + c.w;
    sh[tid] = tsum;
    __syncthreads();
#pragma unroll
    for (int off = 1; off < 256; off <<= 1) {
        int v = (tid >= off) ? sh[tid - off] : 0;
        __syncthreads();
        sh[tid] += v;
        __syncthreads();
    }
    int base = bsum[blockIdx.x] + sh[tid] - tsum;
    if (idx4 < n4) {
        int4 r;
        r.x = base;
        r.y = base + c.x;
        r.z = r.y + c.y;
        r.w = r.z + c.z;
        ((int4*)rowptr)[idx4] = r;
        if (idx4 == n4 - 1) rowptr[N] = r.w + c.w;
    }
}

__global__ __launch_bounds__(256) void place_kernel(
    const int* __restrict__ src, const int* __restrict__ tgt,
    const int* __restrict__ rowptr,
    int* __restrict__ cursor, int* __restrict__ eid, int E)
{
    int e = blockIdx.x * 256 + threadIdx.x;
    if (e >= E) return;
    int t = tgt[e];
    int idx = atomicSub(&cursor[t], 1) - 1;
    eid[rowptr[t] + idx] = src[e];
}

// XCD-sliced gather, node-parallel lanes: slice = blockIdx % 8 keeps each
// 3.2 MB slice table L2-resident. Wave = 16 nodes; lane = nslot*4 + qin.
// Each lane walks its node's edge list sequentially (unroll x4 for MLP) and
// owns exactly one GN group (4 channels) — no cross-lane ops at all.
__global__ __launch_bounds__(256) void gather_gn_kernel(
    const float4* __restrict__ s_sliced, const int* __restrict__ rowptr,
    const int* __restrict__ eid,
    const float* __restrict__ gamma, const float* __restrict__ beta,
    float* __restrict__ out, int N)
{
    const int slice = blockIdx.x & 7;          // blockIdx % NSLICE -> XCD
    const int sblk  = blockIdx.x >> 3;         // block within slice 0..GPB-1
    const int wave  = threadIdx.x >> 6;        // 0..3
    const int lane  = threadIdx.x & 63;
    const int nslot = lane >> 2;               // 0..15: node within wave
    const int qin   = lane & 3;                // float4 within slice

    const float4* stab = s_sliced + (size_t)slice * N_NODES * 4;
    const int gch = slice * 16 + qin * 4;      // first channel of my GN group
    const float4 gm = *(const float4*)&gamma[gch];
    const float4 bt = *(const float4*)&beta[gch];

    const int wslot0  = sblk * 4 + wave;       // wave slot within slice
    const int nwslots = GPB * 4;               // 1024

    for (int base = wslot0 * 16; base < N; base += nwslots * 16) {
        int node = base + nslot;
        bool valid = node < N;
        int beg = 0, end = 0;
        if (valid) {
            beg = rowptr[node];
            end = rowptr[node + 1];
        }

        float4 acc = make_float4(0.f, 0.f, 0.f, 0.f);
        int e = beg;
        for (; e + 3 < end; e += 4) {          // 4 independent loads in flight
            int s0 = eid[e];
            int s1 = eid[e + 1];
            int s2 = eid[e + 2];
            int s3 = eid[e + 3];
            float4 v0 = stab[(size_t)s0 * 4 + qin];
            float4 v1 = stab[(size_t)s1 * 4 + qin];
            float4 v2 = stab[(size_t)s2 * 4 + qin];
            float4 v3 = stab[(size_t)s3 * 4 + qin];
            acc.x += (v0.x + v1.x) + (v2.x + v3.x);
            acc.y += (v0.y + v1.y) + (v2.y + v3.y);
            acc.z += (v0.z + v1.z) + (v2.z + v3.z);
            acc.w += (v0.w + v1.w) + (v2.w + v3.w);
        }
        for (; e < end; ++e) {
            int s = eid[e];
            float4 v = stab[(size_t)s * 4 + qin];
            acc.x += v.x;
            acc.y += v.y;
            acc.z += v.z;
            acc.w += v.w;
        }

        if (valid) {
            int deg = end - beg;
            float inv = (deg > 0) ? (1.0f / (float)deg) : 0.0f;
            float ax = fmaxf(acc.x * inv, 0.f);
            float ay = fmaxf(acc.y * inv, 0.f);
            float az = fmaxf(acc.z * inv, 0.f);
            float aw = fmaxf(acc.w * inv, 0.f);
            float mu = 0.25f * (ax + ay + az + aw);
            float dx = ax - mu, dy = ay - mu, dz = az - mu, dw = aw - mu;
            float var = 0.25f * (dx * dx + dy * dy + dz * dz + dw * dw);
            float rs = rsqrtf(var + EPS);
            float4 r;
            r.x = dx * rs * gm.x + bt.x;
            r.y = dy * rs * gm.y + bt.y;
            r.z = dz * rs * gm.z + bt.z;
            r.w = dw * rs * gm.w + bt.w;
            *(float4*)&out[(size_t)node * DIM + gch] = r;
        }
    }
}

extern "C" void kernel_launch(void* const* d_in, const int* in_sizes, int n_in,
                              void* d_out, int out_size, void* d_ws, size_t ws_size,
                              hipStream_t stream) {
    const float* t      = (const float*)d_in[0];
    const float* x      = (const float*)d_in[1];
    const int*   src    = (const int*)d_in[2];
    const int*   tgt    = (const int*)d_in[3];
    const float* W1     = (const float*)d_in[5];
    const float* b1     = (const float*)d_in[6];
    const float* W2     = (const float*)d_in[7];
    const float* b2     = (const float*)d_in[8];
    const float* gamma1 = (const float*)d_in[9];
    const float* beta1  = (const float*)d_in[10];
    const float* gamma2 = (const float*)d_in[11];
    const float* beta2  = (const float*)d_in[12];
    float* out = (float*)d_out;

    const size_t NODE_BYTES = (size_t)N_NODES * DIM * sizeof(float);  // 25.6 MB
    char* ws = (char*)d_ws;
    size_t off = 0;
    float4* s_sliced = (float4*)(ws + off); off += NODE_BYTES;            // 25.6 MB
    int*    rowptr   = (int*)(ws + off);    off += ((size_t)N_NODES + 4) * 4;
    off = (off + 255) & ~(size_t)255;
    int*    cursor   = (int*)(ws + off);    off += ((size_t)N_NODES + 64) * 4;  // counts + done flag
    int*    done     = cursor + N_NODES;
    off = (off + 255) & ~(size_t)255;
    int*    bsum     = (int*)(ws + off);    off += 64 * 4;
    off = (off + 255) & ~(size_t)255;
    int*    eid      = (int*)(ws + off);    off += (size_t)N_EDGES * 4;   // 2.4 MB

    const int gemm_grid   = (N_NODES + NPB - 1) / NPB;     // 782
    const int edge_grid   = (N_EDGES + 255) / 256;         // 2344
    const int gather_grid = NSLICE * GPB;                  // 2048

    // ---- CSR build (shared by both layers) ----
    hipMemsetAsync(cursor, 0, ((size_t)N_NODES + 64) * 4, stream);  // counts + done
    hist_kernel<<<edge_grid, 256, 0, stream>>>(tgt, cursor, N_EDGES);      // cursor = counts
    scan_pass1<<<SCAN_NB, 256, 0, stream>>>(cursor, bsum, done, N_NODES);  // + bsum scan (last block)
    scan_pass3<<<SCAN_NB, 256, 0, stream>>>(cursor, bsum, rowptr, N_NODES);
    place_kernel<<<edge_grid, 256, 0, stream>>>(src, tgt, rowptr, cursor, eid, N_EDGES);

    // ---- layer 1 ----  (h lives in d_out; gemm2 consumes it before gather2 overwrites)
    gemm_kernel<<<gemm_grid, 256, 0, stream>>>(x, W1, b1, t, s_sliced, N_NODES);
    gather_gn_kernel<<<gather_grid, 256, 0, stream>>>(s_sliced, rowptr, eid, gamma1, beta1, out, N_NODES);

    // ---- layer 2 ----
    gemm_kernel<<<gemm_grid, 256, 0, stream>>>(out, W2, b2, t, s_sliced, N_NODES);
    gather_gn_kernel<<<gather_grid, 256, 0, stream>>>(s_sliced, rowptr, eid, gamma2, beta2, out, N_NODES);
}